// Round 4
// baseline (18442.355 us; speedup 1.0000x reference)
//
#include <hip/hip_runtime.h>
#include <cmath>

typedef _Float16 f16;
typedef _Float16 f16x8 __attribute__((ext_vector_type(8)));
typedef _Float16 f16x4 __attribute__((ext_vector_type(4)));
typedef float f32x4 __attribute__((ext_vector_type(4)));

#define H_DIM 1024
#define I_DIMM 256
#define B_DIM 64
#define T_DIM 256
#define K_DIM 1280
#define NBLK 256

// Build W16[4096][1280] = fp16([Whh | Wih]) row-major. grid = 4096 blocks.
__global__ __launch_bounds__(256) void conv_w_kernel(const float* __restrict__ Whh,
                                                     const float* __restrict__ Wih,
                                                     f16* __restrict__ W16) {
    const int r = blockIdx.x;
    const int tid = threadIdx.x;
    const float* hh = Whh + (size_t)r * H_DIM;
    const float* ih = Wih + (size_t)r * I_DIMM;
    f16* dst = W16 + (size_t)r * K_DIM;
    for (int k = tid; k < K_DIM; k += 256)
        dst[k] = (f16)(k < H_DIM ? hh[k] : ih[k - H_DIM]);
}

// x fp32 -> fp16, vectorized 4-wide. n4 = total/4.
__global__ __launch_bounds__(256) void conv_x_kernel(const float* __restrict__ x,
                                                     f16* __restrict__ x16, int n4) {
    const int i = blockIdx.x * 256 + threadIdx.x;
    if (i < n4) {
        float4 v = ((const float4*)x)[i];
        f16x4 o;
        o[0] = (f16)v.x; o[1] = (f16)v.y; o[2] = (f16)v.z; o[3] = (f16)v.w;
        ((f16x4*)x16)[i] = o;
    }
}

// Persistent LSTM, both phases, 512 steps, one cooperative launch.
// grid = 256 blocks x 256 threads (1 block/CU). Block owns h-cols
// [blk*4, blk*4+4) x 4 gates = 16 W rows, staged in LDS (40 KB) per phase.
// Waves are K-split: wave w owns k in [w*320,(w+1)*320), computes partial
// gates for all 64 batch x 16 gate cols (4 MFMA tiles x 10 k-steps, W frag
// shared across the 4 batch tiles). Partials reduced through LDS.
// Hand-rolled grid barrier: monotone agent-scope counter + explicit fences.
__global__ __launch_bounds__(256, 1) void lstm_persistent(
    f16* __restrict__ h0,            // [64][1024] ping
    f16* __restrict__ h1,            // [64][1024] pong
    const f16* __restrict__ x16,     // [64][256][256]
    const f16* __restrict__ W16e,    // [4096][1280]
    const f16* __restrict__ W16d,    // [4096][1280]
    const float* __restrict__ enc_bih, const float* __restrict__ enc_bhh,
    const float* __restrict__ dec_bih, const float* __restrict__ dec_bhh,
    unsigned* bar)
{
    __shared__ f16  lds_w[40 * 64 * 8];   // 40 KB: [slot = w*10+it][lane][8 f16]
    __shared__ float gpart[4][64][17];    // [kwave][batch][gate-col], +1 pad

    const int tid  = threadIdx.x;
    const int blk  = blockIdx.x;
    const int w    = tid >> 6;            // K-quarter this wave owns
    const int lane = tid & 63;
    const int n    = lane & 15;
    const int kg   = lane >> 4;
    const int kg8  = kg * 8;

    // this lane's W row (16x16x32 B-operand col = n), verified in round 2
    const int rW   = (n >> 2) * H_DIM + blk * 4 + (n & 3);

    // activation-thread mapping
    const int ab   = tid >> 2;
    const int aj   = tid & 3;
    const int acol = blk * 4 + aj;

    float c_reg = 0.f;                    // carries enc -> dec
    unsigned bar_target = 0;
    const int w320 = w * 320;

    #pragma unroll 1
    for (int phase = 0; phase < 2; ++phase) {
        const f16* W  = phase ? W16d : W16e;
        const float* bi = phase ? dec_bih : enc_bih;
        const float* bh = phase ? dec_bhh : enc_bhh;

        float bsum[4];
        #pragma unroll
        for (int g = 0; g < 4; ++g)
            bsum[g] = bi[g * H_DIM + acol] + bh[g * H_DIM + acol];

        // Stage this wave's 10 W fragments/lane into LDS, in consumption order.
        // Wave w writes and reads only slots [w*10, w*10+10) -> no block barrier.
        {
            const f16* pw = W + (size_t)rW * K_DIM + w320 + kg8;
            f16* dst = lds_w + ((size_t)(w * 10) * 64 + lane) * 8;
            #pragma unroll
            for (int it = 0; it < 10; ++it)
                *(f16x8*)(dst + (size_t)it * 64 * 8) = *(const f16x8*)(pw + it * 32);
        }

        #pragma unroll 1
        for (int t = 0; t < T_DIM; ++t) {
            const f16* hi = (t & 1) ? h1 : h0;
            f16*       ho = (t & 1) ? h0 : h1;
            const f16* xt = x16 + (size_t)t * I_DIMM;

            f32x4 a0 = {0.f,0.f,0.f,0.f}, a1 = {0.f,0.f,0.f,0.f};
            f32x4 a2 = {0.f,0.f,0.f,0.f}, a3 = {0.f,0.f,0.f,0.f};

            #pragma unroll
            for (int it = 0; it < 10; ++it) {
                f16x8 wf = *(const f16x8*)(lds_w + ((size_t)(w * 10 + it) * 64 + lane) * 8);
                const int k0 = w320 + it * 32;
                const f16* ap; int astr;
                if (k0 < 1024) { ap = hi + k0 + kg8;            astr = H_DIM; }
                else           { ap = xt + (k0 - 1024) + kg8;   astr = T_DIM * I_DIMM; }
                f16x8 f0 = *(const f16x8*)(ap + (size_t)(n)      * astr);
                f16x8 f1 = *(const f16x8*)(ap + (size_t)(n + 16) * astr);
                f16x8 f2 = *(const f16x8*)(ap + (size_t)(n + 32) * astr);
                f16x8 f3 = *(const f16x8*)(ap + (size_t)(n + 48) * astr);
                a0 = __builtin_amdgcn_mfma_f32_16x16x32_f16(f0, wf, a0, 0, 0, 0);
                a1 = __builtin_amdgcn_mfma_f32_16x16x32_f16(f1, wf, a1, 0, 0, 0);
                a2 = __builtin_amdgcn_mfma_f32_16x16x32_f16(f2, wf, a2, 0, 0, 0);
                a3 = __builtin_amdgcn_mfma_f32_16x16x32_f16(f3, wf, a3, 0, 0, 0);
            }

            // partials: D row = batch_tile*16 + 4*kg + r, col = n
            #pragma unroll
            for (int r = 0; r < 4; ++r) {
                gpart[w][ 0 + kg * 4 + r][n] = a0[r];
                gpart[w][16 + kg * 4 + r][n] = a1[r];
                gpart[w][32 + kg * 4 + r][n] = a2[r];
                gpart[w][48 + kg * 4 + r][n] = a3[r];
            }
            __syncthreads();

            // activations + state update
            float pre[4];
            #pragma unroll
            for (int g = 0; g < 4; ++g)
                pre[g] = gpart[0][ab][g * 4 + aj] + gpart[1][ab][g * 4 + aj]
                       + gpart[2][ab][g * 4 + aj] + gpart[3][ab][g * 4 + aj] + bsum[g];
            const float i_ = 1.f / (1.f + expf(-pre[0]));
            const float f_ = 1.f / (1.f + expf(-pre[1]));
            const float g_ = tanhf(pre[2]);
            const float o_ = 1.f / (1.f + expf(-pre[3]));
            c_reg = f_ * c_reg + i_ * g_;
            ho[(size_t)ab * H_DIM + acol] = (f16)(o_ * tanhf(c_reg));

            // ---- grid barrier: release, arrive, spin, acquire ----
            __builtin_amdgcn_fence(__ATOMIC_RELEASE, "agent");
            __syncthreads();                 // all waves' h stores flushed
            bar_target += NBLK;
            if (tid == 0) {
                __hip_atomic_fetch_add(bar, 1u, __ATOMIC_RELAXED, __HIP_MEMORY_SCOPE_AGENT);
                while (__hip_atomic_load(bar, __ATOMIC_RELAXED, __HIP_MEMORY_SCOPE_AGENT) < bar_target)
                    __builtin_amdgcn_s_sleep(2);
            }
            __syncthreads();
            __builtin_amdgcn_fence(__ATOMIC_ACQUIRE, "agent");
        }
    }
}

// Tail MLP: a = PReLU(additional @ fcc_W^T + fcc_b); out[b] = [dh, a] @ fc_W^T + fc_b
__global__ __launch_bounds__(256) void tail_kernel(
    const f16* __restrict__ dh,        // [64][1024] fp16
    const float* __restrict__ addl,    // [64][128]
    const float* __restrict__ fccW,    // [256][128]
    const float* __restrict__ fccb,    // [256]
    const float* __restrict__ fcW,     // [1][1280]
    const float* __restrict__ fcb,     // [1]
    const float* __restrict__ prelu_a, // [1]
    float* __restrict__ out)           // [64]
{
    __shared__ float a_lds[256];
    __shared__ float red[256];
    const int b = blockIdx.x;
    const int t = threadIdx.x;

    float s = fccb[t];
    const float* wr = fccW + t * 128;
    const float* ar = addl + b * 128;
    #pragma unroll 4
    for (int k = 0; k < 128; ++k) s += ar[k] * wr[k];
    const float pa = *prelu_a;
    a_lds[t] = (s >= 0.f) ? s : pa * s;
    __syncthreads();

    float acc = 0.f;
    for (int k = t; k < 1024; k += 256) acc += (float)dh[b * H_DIM + k] * fcW[k];
    acc += a_lds[t] * fcW[1024 + t];
    red[t] = acc;
    __syncthreads();
    for (int sft = 128; sft > 0; sft >>= 1) {
        if (t < sft) red[t] += red[t + sft];
        __syncthreads();
    }
    if (t == 0) out[b] = red[0] + fcb[0];
}

extern "C" void kernel_launch(void* const* d_in, const int* in_sizes, int n_in,
                              void* d_out, int out_size, void* d_ws, size_t ws_size,
                              hipStream_t stream)
{
    const float* x       = (const float*)d_in[0];
    const float* addl    = (const float*)d_in[1];
    const float* enc_Wih = (const float*)d_in[2];
    const float* enc_Whh = (const float*)d_in[3];
    const float* enc_bih = (const float*)d_in[4];
    const float* enc_bhh = (const float*)d_in[5];
    const float* dec_Wih = (const float*)d_in[6];
    const float* dec_Whh = (const float*)d_in[7];
    const float* dec_bih = (const float*)d_in[8];
    const float* dec_bhh = (const float*)d_in[9];
    const float* fcc_W   = (const float*)d_in[10];
    const float* fcc_b   = (const float*)d_in[11];
    const float* fc_W    = (const float*)d_in[12];
    const float* fc_b    = (const float*)d_in[13];
    const float* prelu_a = (const float*)d_in[14];

    char* wsb = (char*)d_ws;
    const size_t W16_BYTES = (size_t)4 * H_DIM * K_DIM * sizeof(f16);   // 10.5 MB
    const size_t X16_BYTES = (size_t)B_DIM * T_DIM * I_DIMM * sizeof(f16);
    const size_t H16_BYTES = (size_t)B_DIM * H_DIM * sizeof(f16);

    f16* W16e = (f16*)wsb;                      wsb += W16_BYTES;
    f16* W16d = (f16*)wsb;                      wsb += W16_BYTES;
    f16* x16  = (f16*)wsb;                      wsb += X16_BYTES;
    f16* h0   = (f16*)wsb;                      wsb += H16_BYTES;
    f16* h1   = (f16*)wsb;                      wsb += H16_BYTES;
    unsigned* bar = (unsigned*)wsb;

    // One-time (per call) conversions + state init.
    conv_w_kernel<<<4 * H_DIM, 256, 0, stream>>>(enc_Whh, enc_Wih, W16e);
    conv_w_kernel<<<4 * H_DIM, 256, 0, stream>>>(dec_Whh, dec_Wih, W16d);
    conv_x_kernel<<<(B_DIM * T_DIM * I_DIMM / 4 + 255) / 256, 256, 0, stream>>>(
        x, x16, B_DIM * T_DIM * I_DIMM / 4);
    hipMemsetAsync(h0, 0, H16_BYTES, stream);
    hipMemsetAsync(bar, 0, 128, stream);   // barrier counter must start at 0 every call

    // Persistent cooperative kernel: both LSTMs, 512 steps, one launch.
    {
        void* args[] = { &h0, &h1, &x16, &W16e, &W16d,
                         &enc_bih, &enc_bhh, &dec_bih, &dec_bhh, &bar };
        hipLaunchCooperativeKernel((void*)lstm_persistent, dim3(NBLK), dim3(256),
                                   args, 0, stream);
    }

    // Final dec h is in h0 (256 steps per phase, even count).
    tail_kernel<<<64, 256, 0, stream>>>(h0, addl, fcc_W, fcc_b, fc_W, fc_b,
                                        prelu_a, (float*)d_out);
}

// Round 5
// 17534.926 us; speedup vs baseline: 1.0517x; 1.0517x over previous
//
#include <hip/hip_runtime.h>
#include <cmath>

typedef _Float16 f16;
typedef _Float16 f16x8 __attribute__((ext_vector_type(8)));
typedef _Float16 f16x4 __attribute__((ext_vector_type(4)));
typedef float f32x4 __attribute__((ext_vector_type(4)));

#define H_DIM 1024
#define I_DIMM 256
#define B_DIM 64
#define T_DIM 256
#define K_DIM 1280
#define NBLK 256

// Build W16[4096][1280] = fp16([Whh | Wih]) row-major. grid = 4096 blocks.
__global__ __launch_bounds__(256) void conv_w_kernel(const float* __restrict__ Whh,
                                                     const float* __restrict__ Wih,
                                                     f16* __restrict__ W16) {
    const int r = blockIdx.x;
    const int tid = threadIdx.x;
    const float* hh = Whh + (size_t)r * H_DIM;
    const float* ih = Wih + (size_t)r * I_DIMM;
    f16* dst = W16 + (size_t)r * K_DIM;
    for (int k = tid; k < K_DIM; k += 256)
        dst[k] = (f16)(k < H_DIM ? hh[k] : ih[k - H_DIM]);
}

// x fp32 -> fp16, vectorized 4-wide. n4 = total/4.
__global__ __launch_bounds__(256) void conv_x_kernel(const float* __restrict__ x,
                                                     f16* __restrict__ x16, int n4) {
    const int i = blockIdx.x * 256 + threadIdx.x;
    if (i < n4) {
        float4 v = ((const float4*)x)[i];
        f16x4 o;
        o[0] = (f16)v.x; o[1] = (f16)v.y; o[2] = (f16)v.z; o[3] = (f16)v.w;
        ((f16x4*)x16)[i] = o;
    }
}

// Persistent LSTM, both phases, 512 steps, one cooperative launch.
// grid = 256 blocks x 256 threads (1 block/CU). Block owns h-cols
// [blk*4, blk*4+4) x 4 gates = 16 W rows, staged in LDS (40 KB) per phase.
// Waves are K-split; partials reduced through LDS. Cell state in a register.
//
// Grid barrier = flag array with monotone epochs:
//   arrive: per-block agent-scope STORE (parallel, no RMW serialization)
//   wait:   thread tid polls flags[tid] with agent-scope loads (bypass L2)
// This replaces round 4's single-counter atomicAdd arrival, whose 256
// serialized cross-XCD RMWs (~130 ns each ~= 33 us) dominated the step.
__global__ __launch_bounds__(256, 1) void lstm_persistent(
    f16* __restrict__ h0,            // [64][1024] ping
    f16* __restrict__ h1,            // [64][1024] pong
    const f16* __restrict__ x16,     // [64][256][256]
    const f16* __restrict__ W16e,    // [4096][1280]
    const f16* __restrict__ W16d,    // [4096][1280]
    const float* __restrict__ enc_bih, const float* __restrict__ enc_bhh,
    const float* __restrict__ dec_bih, const float* __restrict__ dec_bhh,
    unsigned* __restrict__ flags)    // [256], zeroed each call
{
    __shared__ f16  lds_w[40 * 64 * 8];   // 40 KB: [slot = w*10+it][lane][8 f16]
    __shared__ float gpart[4][64][17];    // [kwave][batch][gate-col], +1 pad

    const int tid  = threadIdx.x;
    const int blk  = blockIdx.x;
    const int w    = tid >> 6;            // K-quarter this wave owns
    const int lane = tid & 63;
    const int n    = lane & 15;
    const int kg   = lane >> 4;
    const int kg8  = kg * 8;

    // this lane's W row (16x16x32 B-operand col = n), verified in round 2
    const int rW   = (n >> 2) * H_DIM + blk * 4 + (n & 3);

    // activation-thread mapping
    const int ab   = tid >> 2;
    const int aj   = tid & 3;
    const int acol = blk * 4 + aj;

    float c_reg = 0.f;                    // carries enc -> dec
    unsigned stepv = 0;                   // monotone barrier epoch
    const int w320 = w * 320;

    #pragma unroll 1
    for (int phase = 0; phase < 2; ++phase) {
        const f16* W  = phase ? W16d : W16e;
        const float* bi = phase ? dec_bih : enc_bih;
        const float* bh = phase ? dec_bhh : enc_bhh;

        float bsum[4];
        #pragma unroll
        for (int g = 0; g < 4; ++g)
            bsum[g] = bi[g * H_DIM + acol] + bh[g * H_DIM + acol];

        // Stage this wave's 10 W fragments/lane into LDS, in consumption order.
        // Wave w writes and reads only slots [w*10, w*10+10) -> no block barrier.
        {
            const f16* pw = W + (size_t)rW * K_DIM + w320 + kg8;
            f16* dst = lds_w + ((size_t)(w * 10) * 64 + lane) * 8;
            #pragma unroll
            for (int it = 0; it < 10; ++it)
                *(f16x8*)(dst + (size_t)it * 64 * 8) = *(const f16x8*)(pw + it * 32);
        }

        #pragma unroll 1
        for (int t = 0; t < T_DIM; ++t) {
            const f16* hi = (t & 1) ? h1 : h0;
            f16*       ho = (t & 1) ? h0 : h1;
            const f16* xt = x16 + (size_t)t * I_DIMM;

            f32x4 a0 = {0.f,0.f,0.f,0.f}, a1 = {0.f,0.f,0.f,0.f};
            f32x4 a2 = {0.f,0.f,0.f,0.f}, a3 = {0.f,0.f,0.f,0.f};

            #pragma unroll
            for (int it = 0; it < 10; ++it) {
                f16x8 wf = *(const f16x8*)(lds_w + ((size_t)(w * 10 + it) * 64 + lane) * 8);
                const int k0 = w320 + it * 32;
                const f16* ap; int astr;
                if (k0 < 1024) { ap = hi + k0 + kg8;            astr = H_DIM; }
                else           { ap = xt + (k0 - 1024) + kg8;   astr = T_DIM * I_DIMM; }
                f16x8 f0 = *(const f16x8*)(ap + (size_t)(n)      * astr);
                f16x8 f1 = *(const f16x8*)(ap + (size_t)(n + 16) * astr);
                f16x8 f2 = *(const f16x8*)(ap + (size_t)(n + 32) * astr);
                f16x8 f3 = *(const f16x8*)(ap + (size_t)(n + 48) * astr);
                a0 = __builtin_amdgcn_mfma_f32_16x16x32_f16(f0, wf, a0, 0, 0, 0);
                a1 = __builtin_amdgcn_mfma_f32_16x16x32_f16(f1, wf, a1, 0, 0, 0);
                a2 = __builtin_amdgcn_mfma_f32_16x16x32_f16(f2, wf, a2, 0, 0, 0);
                a3 = __builtin_amdgcn_mfma_f32_16x16x32_f16(f3, wf, a3, 0, 0, 0);
            }

            // partials: D row = batch_tile*16 + 4*kg + r, col = n
            #pragma unroll
            for (int r = 0; r < 4; ++r) {
                gpart[w][ 0 + kg * 4 + r][n] = a0[r];
                gpart[w][16 + kg * 4 + r][n] = a1[r];
                gpart[w][32 + kg * 4 + r][n] = a2[r];
                gpart[w][48 + kg * 4 + r][n] = a3[r];
            }
            __syncthreads();

            // activations + state update
            float pre[4];
            #pragma unroll
            for (int g = 0; g < 4; ++g)
                pre[g] = gpart[0][ab][g * 4 + aj] + gpart[1][ab][g * 4 + aj]
                       + gpart[2][ab][g * 4 + aj] + gpart[3][ab][g * 4 + aj] + bsum[g];
            const float i_ = 1.f / (1.f + expf(-pre[0]));
            const float f_ = 1.f / (1.f + expf(-pre[1]));
            const float g_ = tanhf(pre[2]);
            const float o_ = 1.f / (1.f + expf(-pre[3]));
            c_reg = f_ * c_reg + i_ * g_;
            ho[(size_t)ab * H_DIM + acol] = (f16)(o_ * tanhf(c_reg));

            // ---- grid barrier: release, flag-store arrive, parallel poll, acquire ----
            ++stepv;
            __builtin_amdgcn_fence(__ATOMIC_RELEASE, "agent");
            __syncthreads();                 // all waves' h stores at coherence point
            if (tid == 0)
                __hip_atomic_store(&flags[blk], stepv,
                                   __ATOMIC_RELAXED, __HIP_MEMORY_SCOPE_AGENT);
            while (__hip_atomic_load(&flags[tid],
                                     __ATOMIC_RELAXED, __HIP_MEMORY_SCOPE_AGENT) < stepv)
                __builtin_amdgcn_s_sleep(1);
            __syncthreads();
            __builtin_amdgcn_fence(__ATOMIC_ACQUIRE, "agent");
        }
    }
}

// Tail MLP: a = PReLU(additional @ fcc_W^T + fcc_b); out[b] = [dh, a] @ fc_W^T + fc_b
__global__ __launch_bounds__(256) void tail_kernel(
    const f16* __restrict__ dh,        // [64][1024] fp16
    const float* __restrict__ addl,    // [64][128]
    const float* __restrict__ fccW,    // [256][128]
    const float* __restrict__ fccb,    // [256]
    const float* __restrict__ fcW,     // [1][1280]
    const float* __restrict__ fcb,     // [1]
    const float* __restrict__ prelu_a, // [1]
    float* __restrict__ out)           // [64]
{
    __shared__ float a_lds[256];
    __shared__ float red[256];
    const int b = blockIdx.x;
    const int t = threadIdx.x;

    float s = fccb[t];
    const float* wr = fccW + t * 128;
    const float* ar = addl + b * 128;
    #pragma unroll 4
    for (int k = 0; k < 128; ++k) s += ar[k] * wr[k];
    const float pa = *prelu_a;
    a_lds[t] = (s >= 0.f) ? s : pa * s;
    __syncthreads();

    float acc = 0.f;
    for (int k = t; k < 1024; k += 256) acc += (float)dh[b * H_DIM + k] * fcW[k];
    acc += a_lds[t] * fcW[1024 + t];
    red[t] = acc;
    __syncthreads();
    for (int sft = 128; sft > 0; sft >>= 1) {
        if (t < sft) red[t] += red[t + sft];
        __syncthreads();
    }
    if (t == 0) out[b] = red[0] + fcb[0];
}

extern "C" void kernel_launch(void* const* d_in, const int* in_sizes, int n_in,
                              void* d_out, int out_size, void* d_ws, size_t ws_size,
                              hipStream_t stream)
{
    const float* x       = (const float*)d_in[0];
    const float* addl    = (const float*)d_in[1];
    const float* enc_Wih = (const float*)d_in[2];
    const float* enc_Whh = (const float*)d_in[3];
    const float* enc_bih = (const float*)d_in[4];
    const float* enc_bhh = (const float*)d_in[5];
    const float* dec_Wih = (const float*)d_in[6];
    const float* dec_Whh = (const float*)d_in[7];
    const float* dec_bih = (const float*)d_in[8];
    const float* dec_bhh = (const float*)d_in[9];
    const float* fcc_W   = (const float*)d_in[10];
    const float* fcc_b   = (const float*)d_in[11];
    const float* fc_W    = (const float*)d_in[12];
    const float* fc_b    = (const float*)d_in[13];
    const float* prelu_a = (const float*)d_in[14];

    char* wsb = (char*)d_ws;
    const size_t W16_BYTES = (size_t)4 * H_DIM * K_DIM * sizeof(f16);   // 10.5 MB
    const size_t X16_BYTES = (size_t)B_DIM * T_DIM * I_DIMM * sizeof(f16);
    const size_t H16_BYTES = (size_t)B_DIM * H_DIM * sizeof(f16);

    f16* W16e = (f16*)wsb;                      wsb += W16_BYTES;
    f16* W16d = (f16*)wsb;                      wsb += W16_BYTES;
    f16* x16  = (f16*)wsb;                      wsb += X16_BYTES;
    f16* h0   = (f16*)wsb;                      wsb += H16_BYTES;
    f16* h1   = (f16*)wsb;                      wsb += H16_BYTES;
    unsigned* flags = (unsigned*)wsb;

    // One-time (per call) conversions + state init.
    conv_w_kernel<<<4 * H_DIM, 256, 0, stream>>>(enc_Whh, enc_Wih, W16e);
    conv_w_kernel<<<4 * H_DIM, 256, 0, stream>>>(dec_Whh, dec_Wih, W16d);
    conv_x_kernel<<<(B_DIM * T_DIM * I_DIMM / 4 + 255) / 256, 256, 0, stream>>>(
        x, x16, B_DIM * T_DIM * I_DIMM / 4);
    hipMemsetAsync(h0, 0, H16_BYTES, stream);
    hipMemsetAsync(flags, 0, NBLK * sizeof(unsigned), stream);  // epoch 0 each call

    // Persistent cooperative kernel: both LSTMs, 512 steps, one launch.
    {
        void* args[] = { &h0, &h1, &x16, &W16e, &W16d,
                         &enc_bih, &enc_bhh, &dec_bih, &dec_bhh, &flags };
        hipLaunchCooperativeKernel((void*)lstm_persistent, dim3(NBLK), dim3(256),
                                   args, 0, stream);
    }

    // Final dec h is in h0 (256 steps per phase, even count).
    tail_kernel<<<64, 256, 0, stream>>>(h0, addl, fcc_W, fcc_b, fc_W, fc_b,
                                        prelu_a, (float*)d_out);
}

// Round 6
// 7042.946 us; speedup vs baseline: 2.6186x; 2.4897x over previous
//
#include <hip/hip_runtime.h>
#include <cmath>

typedef _Float16 f16;
typedef _Float16 f16x8 __attribute__((ext_vector_type(8)));
typedef _Float16 f16x4 __attribute__((ext_vector_type(4)));
typedef float f32x4 __attribute__((ext_vector_type(4)));
typedef unsigned long long u64;

#define H_DIM 1024
#define I_DIMM 256
#define B_DIM 64
#define T_DIM 256
#define K_DIM 1280
#define NBLK 256

// Build W16[4096][1280] = fp16([Whh | Wih]) row-major. grid = 4096 blocks.
__global__ __launch_bounds__(256) void conv_w_kernel(const float* __restrict__ Whh,
                                                     const float* __restrict__ Wih,
                                                     f16* __restrict__ W16) {
    const int r = blockIdx.x;
    const int tid = threadIdx.x;
    const float* hh = Whh + (size_t)r * H_DIM;
    const float* ih = Wih + (size_t)r * I_DIMM;
    f16* dst = W16 + (size_t)r * K_DIM;
    for (int k = tid; k < K_DIM; k += 256)
        dst[k] = (f16)(k < H_DIM ? hh[k] : ih[k - H_DIM]);
}

// x fp32 -> fp16, vectorized 4-wide. n4 = total/4.
__global__ __launch_bounds__(256) void conv_x_kernel(const float* __restrict__ x,
                                                     f16* __restrict__ x16, int n4) {
    const int i = blockIdx.x * 256 + threadIdx.x;
    if (i < n4) {
        float4 v = ((const float4*)x)[i];
        f16x4 o;
        o[0] = (f16)v.x; o[1] = (f16)v.y; o[2] = (f16)v.z; o[3] = (f16)v.w;
        ((f16x4*)x16)[i] = o;
    }
}

// L2-bypassing 16B h-fragment load as two 8B agent-scope atomic loads.
// Compiler emits global_load_dwordx2 ... sc1 (reads coherence point, never the
// possibly-stale per-XCD L2) and still tracks vmcnt for dependent MFMAs.
__device__ __forceinline__ f16x8 ld_h(const f16* p) {
    union { u64 u[2]; f16x8 v; } U;
    U.u[0] = __hip_atomic_load((const u64*)p,     __ATOMIC_RELAXED, __HIP_MEMORY_SCOPE_AGENT);
    U.u[1] = __hip_atomic_load((const u64*)p + 1, __ATOMIC_RELAXED, __HIP_MEMORY_SCOPE_AGENT);
    return U.v;
}

// Persistent LSTM, both phases, 512 steps, one cooperative launch.
// grid = 256 blocks x 256 threads (1 block/CU). Block owns h-cols
// [blk*4, blk*4+4) x 4 gates = 16 W rows, staged in LDS (40 KB) per phase.
// Waves are K-split; partials reduced through LDS. Cell state in a register.
//
// Cross-step coherence WITHOUT agent fences (no buffer_wbl2 / buffer_inv):
//   - h is the ONLY cross-block data; it moves through the coherence point
//     via sc1 write-through stores (packed 8B atomics) and sc1 bypass loads.
//   - read-only data (W-LDS source, x16, biases) stays cached in L2 forever.
//   - barrier: per-wave s_waitcnt vmcnt(0) (write-through => globally visible)
//     -> __syncthreads -> parallel flag store -> 1:1 flag poll -> __syncthreads.
__global__ __launch_bounds__(256, 1) void lstm_persistent(
    f16* __restrict__ h0,            // [64][1024] ping
    f16* __restrict__ h1,            // [64][1024] pong
    const f16* __restrict__ x16,     // [64][256][256]
    const f16* __restrict__ W16e,    // [4096][1280]
    const f16* __restrict__ W16d,    // [4096][1280]
    const float* __restrict__ enc_bih, const float* __restrict__ enc_bhh,
    const float* __restrict__ dec_bih, const float* __restrict__ dec_bhh,
    unsigned* __restrict__ flags)    // [256], zeroed each call
{
    __shared__ f16  lds_w[40 * 64 * 8];   // 40 KB: [slot = w*10+it][lane][8 f16]
    __shared__ float gpart[4][64][17];    // [kwave][batch][gate-col], +1 pad
    __shared__ __align__(8) f16 h_lds[64][4];  // per-step h output exchange

    const int tid  = threadIdx.x;
    const int blk  = blockIdx.x;
    const int w    = tid >> 6;            // K-quarter this wave owns
    const int lane = tid & 63;
    const int n    = lane & 15;
    const int kg   = lane >> 4;
    const int kg8  = kg * 8;

    // this lane's W row (16x16x32 B-operand col = n), verified in round 2
    const int rW   = (n >> 2) * H_DIM + blk * 4 + (n & 3);

    // activation-thread mapping
    const int ab   = tid >> 2;
    const int aj   = tid & 3;
    const int acol = blk * 4 + aj;

    float c_reg = 0.f;                    // carries enc -> dec
    unsigned stepv = 0;                   // monotone barrier epoch
    const int w320 = w * 320;

    #pragma unroll 1
    for (int phase = 0; phase < 2; ++phase) {
        const f16* W  = phase ? W16d : W16e;
        const float* bi = phase ? dec_bih : enc_bih;
        const float* bh = phase ? dec_bhh : enc_bhh;

        float bsum[4];
        #pragma unroll
        for (int g = 0; g < 4; ++g)
            bsum[g] = bi[g * H_DIM + acol] + bh[g * H_DIM + acol];

        // Stage this wave's 10 W fragments/lane into LDS, in consumption order.
        // Wave w writes and reads only slots [w*10, w*10+10) -> no block barrier.
        {
            const f16* pw = W + (size_t)rW * K_DIM + w320 + kg8;
            f16* dst = lds_w + ((size_t)(w * 10) * 64 + lane) * 8;
            #pragma unroll
            for (int it = 0; it < 10; ++it)
                *(f16x8*)(dst + (size_t)it * 64 * 8) = *(const f16x8*)(pw + it * 32);
        }

        #pragma unroll 1
        for (int t = 0; t < T_DIM; ++t) {
            const f16* hi = (t & 1) ? h1 : h0;
            f16*       ho = (t & 1) ? h0 : h1;
            const f16* xt = x16 + (size_t)t * I_DIMM;

            f32x4 a0 = {0.f,0.f,0.f,0.f}, a1 = {0.f,0.f,0.f,0.f};
            f32x4 a2 = {0.f,0.f,0.f,0.f}, a3 = {0.f,0.f,0.f,0.f};

            #pragma unroll
            for (int it = 0; it < 10; ++it) {
                f16x8 wf = *(const f16x8*)(lds_w + ((size_t)(w * 10 + it) * 64 + lane) * 8);
                const int k0 = w320 + it * 32;
                f16x8 f0, f1, f2, f3;
                if (k0 < 1024) {
                    // h: L2-bypass agent loads (fresh data, no acquire fence needed)
                    const f16* ap = hi + k0 + kg8;
                    f0 = ld_h(ap + (size_t)(n)      * H_DIM);
                    f1 = ld_h(ap + (size_t)(n + 16) * H_DIM);
                    f2 = ld_h(ap + (size_t)(n + 32) * H_DIM);
                    f3 = ld_h(ap + (size_t)(n + 48) * H_DIM);
                } else {
                    // x: read-only, normal cached loads (L2 never invalidated now)
                    const f16* ap = xt + (k0 - 1024) + kg8;
                    f0 = *(const f16x8*)(ap + (size_t)(n)      * (T_DIM * I_DIMM));
                    f1 = *(const f16x8*)(ap + (size_t)(n + 16) * (T_DIM * I_DIMM));
                    f2 = *(const f16x8*)(ap + (size_t)(n + 32) * (T_DIM * I_DIMM));
                    f3 = *(const f16x8*)(ap + (size_t)(n + 48) * (T_DIM * I_DIMM));
                }
                a0 = __builtin_amdgcn_mfma_f32_16x16x32_f16(f0, wf, a0, 0, 0, 0);
                a1 = __builtin_amdgcn_mfma_f32_16x16x32_f16(f1, wf, a1, 0, 0, 0);
                a2 = __builtin_amdgcn_mfma_f32_16x16x32_f16(f2, wf, a2, 0, 0, 0);
                a3 = __builtin_amdgcn_mfma_f32_16x16x32_f16(f3, wf, a3, 0, 0, 0);
            }

            // partials: D row = batch_tile*16 + 4*kg + r, col = n
            #pragma unroll
            for (int r = 0; r < 4; ++r) {
                gpart[w][ 0 + kg * 4 + r][n] = a0[r];
                gpart[w][16 + kg * 4 + r][n] = a1[r];
                gpart[w][32 + kg * 4 + r][n] = a2[r];
                gpart[w][48 + kg * 4 + r][n] = a3[r];
            }
            __syncthreads();

            // activations + state update -> h exchange in LDS
            {
                float pre[4];
                #pragma unroll
                for (int g = 0; g < 4; ++g)
                    pre[g] = gpart[0][ab][g * 4 + aj] + gpart[1][ab][g * 4 + aj]
                           + gpart[2][ab][g * 4 + aj] + gpart[3][ab][g * 4 + aj] + bsum[g];
                const float i_ = 1.f / (1.f + expf(-pre[0]));
                const float f_ = 1.f / (1.f + expf(-pre[1]));
                const float g_ = tanhf(pre[2]);
                const float o_ = 1.f / (1.f + expf(-pre[3]));
                c_reg = f_ * c_reg + i_ * g_;
                h_lds[ab][aj] = (f16)(o_ * tanhf(c_reg));
            }
            __syncthreads();

            // publish this block's 4 h-cols: packed 8B write-through stores
            if (tid < 64) {
                u64 v = *(const u64*)&h_lds[tid][0];
                __hip_atomic_store((u64*)(ho + (size_t)tid * H_DIM + blk * 4), v,
                                   __ATOMIC_RELAXED, __HIP_MEMORY_SCOPE_AGENT);
            }
            // write-through stores: vmcnt(0) => globally visible (no wbl2 needed)
            asm volatile("s_waitcnt vmcnt(0)" ::: "memory");
            __syncthreads();

            // ---- fence-free grid barrier: flag store + 1:1 parallel poll ----
            ++stepv;
            if (tid == 0)
                __hip_atomic_store(&flags[blk], stepv,
                                   __ATOMIC_RELAXED, __HIP_MEMORY_SCOPE_AGENT);
            while (__hip_atomic_load(&flags[tid],
                                     __ATOMIC_RELAXED, __HIP_MEMORY_SCOPE_AGENT) < stepv)
                __builtin_amdgcn_s_sleep(1);
            __syncthreads();
        }
    }
}

// Tail MLP: a = PReLU(additional @ fcc_W^T + fcc_b); out[b] = [dh, a] @ fc_W^T + fc_b
__global__ __launch_bounds__(256) void tail_kernel(
    const f16* __restrict__ dh,        // [64][1024] fp16
    const float* __restrict__ addl,    // [64][128]
    const float* __restrict__ fccW,    // [256][128]
    const float* __restrict__ fccb,    // [256]
    const float* __restrict__ fcW,     // [1][1280]
    const float* __restrict__ fcb,     // [1]
    const float* __restrict__ prelu_a, // [1]
    float* __restrict__ out)           // [64]
{
    __shared__ float a_lds[256];
    __shared__ float red[256];
    const int b = blockIdx.x;
    const int t = threadIdx.x;

    float s = fccb[t];
    const float* wr = fccW + t * 128;
    const float* ar = addl + b * 128;
    #pragma unroll 4
    for (int k = 0; k < 128; ++k) s += ar[k] * wr[k];
    const float pa = *prelu_a;
    a_lds[t] = (s >= 0.f) ? s : pa * s;
    __syncthreads();

    float acc = 0.f;
    for (int k = t; k < 1024; k += 256) acc += (float)dh[b * H_DIM + k] * fcW[k];
    acc += a_lds[t] * fcW[1024 + t];
    red[t] = acc;
    __syncthreads();
    for (int sft = 128; sft > 0; sft >>= 1) {
        if (t < sft) red[t] += red[t + sft];
        __syncthreads();
    }
    if (t == 0) out[b] = red[0] + fcb[0];
}

extern "C" void kernel_launch(void* const* d_in, const int* in_sizes, int n_in,
                              void* d_out, int out_size, void* d_ws, size_t ws_size,
                              hipStream_t stream)
{
    const float* x       = (const float*)d_in[0];
    const float* addl    = (const float*)d_in[1];
    const float* enc_Wih = (const float*)d_in[2];
    const float* enc_Whh = (const float*)d_in[3];
    const float* enc_bih = (const float*)d_in[4];
    const float* enc_bhh = (const float*)d_in[5];
    const float* dec_Wih = (const float*)d_in[6];
    const float* dec_Whh = (const float*)d_in[7];
    const float* dec_bih = (const float*)d_in[8];
    const float* dec_bhh = (const float*)d_in[9];
    const float* fcc_W   = (const float*)d_in[10];
    const float* fcc_b   = (const float*)d_in[11];
    const float* fc_W    = (const float*)d_in[12];
    const float* fc_b    = (const float*)d_in[13];
    const float* prelu_a = (const float*)d_in[14];

    char* wsb = (char*)d_ws;
    const size_t W16_BYTES = (size_t)4 * H_DIM * K_DIM * sizeof(f16);   // 10.5 MB
    const size_t X16_BYTES = (size_t)B_DIM * T_DIM * I_DIMM * sizeof(f16);
    const size_t H16_BYTES = (size_t)B_DIM * H_DIM * sizeof(f16);

    f16* W16e = (f16*)wsb;                      wsb += W16_BYTES;
    f16* W16d = (f16*)wsb;                      wsb += W16_BYTES;
    f16* x16  = (f16*)wsb;                      wsb += X16_BYTES;
    f16* h0   = (f16*)wsb;                      wsb += H16_BYTES;
    f16* h1   = (f16*)wsb;                      wsb += H16_BYTES;
    unsigned* flags = (unsigned*)wsb;

    // One-time (per call) conversions + state init.
    conv_w_kernel<<<4 * H_DIM, 256, 0, stream>>>(enc_Whh, enc_Wih, W16e);
    conv_w_kernel<<<4 * H_DIM, 256, 0, stream>>>(dec_Whh, dec_Wih, W16d);
    conv_x_kernel<<<(B_DIM * T_DIM * I_DIMM / 4 + 255) / 256, 256, 0, stream>>>(
        x, x16, B_DIM * T_DIM * I_DIMM / 4);
    hipMemsetAsync(h0, 0, H16_BYTES, stream);
    hipMemsetAsync(flags, 0, NBLK * sizeof(unsigned), stream);  // epoch 0 each call

    // Persistent cooperative kernel: both LSTMs, 512 steps, one launch.
    {
        void* args[] = { &h0, &h1, &x16, &W16e, &W16d,
                         &enc_bih, &enc_bhh, &dec_bih, &dec_bhh, &flags };
        hipLaunchCooperativeKernel((void*)lstm_persistent, dim3(NBLK), dim3(256),
                                   args, 0, stream);
    }

    // Final dec h is in h0 (256 steps per phase, even count).
    tail_kernel<<<64, 256, 0, stream>>>(h0, addl, fcc_W, fcc_b, fc_W, fc_b,
                                        prelu_a, (float*)d_out);
}

// Round 7
// 5463.124 us; speedup vs baseline: 3.3758x; 1.2892x over previous
//
#include <hip/hip_runtime.h>
#include <cmath>

typedef _Float16 f16;
typedef _Float16 f16x8 __attribute__((ext_vector_type(8)));
typedef _Float16 f16x4 __attribute__((ext_vector_type(4)));
typedef float f32x4 __attribute__((ext_vector_type(4)));
typedef unsigned long long u64;

#define H_DIM 1024
#define I_DIMM 256
#define B_DIM 64
#define T_DIM 256
#define K_DIM 1280
#define NBLK 128   // blocks; each owns 8 h-cols

// Build W16[4096][1280] = fp16([Whh | Wih]) row-major. grid = 4096 blocks.
__global__ __launch_bounds__(256) void conv_w_kernel(const float* __restrict__ Whh,
                                                     const float* __restrict__ Wih,
                                                     f16* __restrict__ W16) {
    const int r = blockIdx.x;
    const int tid = threadIdx.x;
    const float* hh = Whh + (size_t)r * H_DIM;
    const float* ih = Wih + (size_t)r * I_DIMM;
    f16* dst = W16 + (size_t)r * K_DIM;
    for (int k = tid; k < K_DIM; k += 256)
        dst[k] = (f16)(k < H_DIM ? hh[k] : ih[k - H_DIM]);
}

// x fp32 -> fp16, vectorized 4-wide. n4 = total/4.
__global__ __launch_bounds__(256) void conv_x_kernel(const float* __restrict__ x,
                                                     f16* __restrict__ x16, int n4) {
    const int i = blockIdx.x * 256 + threadIdx.x;
    if (i < n4) {
        float4 v = ((const float4*)x)[i];
        f16x4 o;
        o[0] = (f16)v.x; o[1] = (f16)v.y; o[2] = (f16)v.z; o[3] = (f16)v.w;
        ((f16x4*)x16)[i] = o;
    }
}

// Persistent LSTM, both phases, 512 steps, one cooperative launch.
// grid = 128 blocks x 256 threads (1 block/CU). Block owns h-cols
// [blk*8, blk*8+8) x 4 gates = 32 W rows (80 KB LDS, staged once per phase).
// K split by chunk-interleave: chunk c (32 k's) -> wave c&3, iter c>>2.
//   iters 0..7  : h-part (k < 1024)   -- after the grid barrier
//   iters 8..9  : x-part (k >= 1024)  -- BEFORE the barrier (h-independent,
//                                        overlaps the barrier wait)
// h-part loads: all 32 fragments prefetched into VGPRs (64 x 8B sc1 loads)
// in one burst -> single L3 latency instead of serialized batches.
// Cross-step coherence stays fence-free (sc1 write-through h stores + sc1
// bypass h loads + flag-array barrier with monotone epochs).
__global__ __launch_bounds__(256, 1) void lstm_persistent(
    f16* __restrict__ h0,            // [64][1024] ping
    f16* __restrict__ h1,            // [64][1024] pong
    const f16* __restrict__ x16,     // [64][256][256]
    const f16* __restrict__ W16e,    // [4096][1280]
    const f16* __restrict__ W16d,    // [4096][1280]
    const float* __restrict__ enc_bih, const float* __restrict__ enc_bhh,
    const float* __restrict__ dec_bih, const float* __restrict__ dec_bhh,
    unsigned* __restrict__ flags)    // [NBLK], zeroed each call
{
    __shared__ f16  lds_w[2][40][64][8];        // 80 KB: [ctile][chunk][lane][8 f16]
    __shared__ float gpart[4][64][33];          // 33.8 KB: [kwave][batch][gatecol]+pad
    __shared__ __align__(16) f16 h_lds[64][8];  // per-step h output exchange

    const int tid  = threadIdx.x;
    const int blk  = blockIdx.x;
    const int w    = tid >> 6;            // wave id = K-interleave class
    const int lane = tid & 63;
    const int n    = lane & 15;
    const int kg   = lane >> 4;
    const int kg8  = kg * 8;
    const int w32  = w * 32;

    // W rows for this lane's two column-tiles (gate-col = ct*16 + n)
    int rW[2];
    #pragma unroll
    for (int ct = 0; ct < 2; ++ct) {
        const int gc = ct * 16 + n;                       // [0,32)
        rW[ct] = (gc >> 3) * H_DIM + blk * 8 + (gc & 7);  // gate*H + col
    }

    // activation-thread mapping: thread -> (batch ab, cols jj and jj+4)
    const int ab    = tid >> 2;
    const int jj    = tid & 3;
    const int acol0 = blk * 8 + jj;
    const int acol1 = acol0 + 4;

    float c0 = 0.f, c1 = 0.f;             // cell state, carries enc -> dec
    unsigned stepv = 0;                   // monotone barrier epoch

    #pragma unroll 1
    for (int phase = 0; phase < 2; ++phase) {
        const f16* W  = phase ? W16d : W16e;
        const float* bi = phase ? dec_bih : enc_bih;
        const float* bh = phase ? dec_bhh : enc_bhh;

        float bsum[4][2];
        #pragma unroll
        for (int g = 0; g < 4; ++g) {
            bsum[g][0] = bi[g * H_DIM + acol0] + bh[g * H_DIM + acol0];
            bsum[g][1] = bi[g * H_DIM + acol1] + bh[g * H_DIM + acol1];
        }

        // Stage W chunks (wave-private slots c = it*4+w -> no barrier needed).
        #pragma unroll 1
        for (int it = 0; it < 10; ++it) {
            const int c = it * 4 + w;
            #pragma unroll
            for (int ct = 0; ct < 2; ++ct)
                *(f16x8*)&lds_w[ct][c][lane][0] =
                    *(const f16x8*)(W + (size_t)rW[ct] * K_DIM + c * 32 + kg8);
        }

        #pragma unroll 1
        for (int t = 0; t < T_DIM; ++t) {
            const f16* hi = (t & 1) ? h1 : h0;
            f16*       ho = (t & 1) ? h0 : h1;
            const f16* xt = x16 + (size_t)t * I_DIMM;

            f32x4 acc[2][4];
            #pragma unroll
            for (int ct = 0; ct < 2; ++ct)
                #pragma unroll
                for (int bt = 0; bt < 4; ++bt)
                    acc[ct][bt] = (f32x4){0.f, 0.f, 0.f, 0.f};

            // ---- x-part (h-independent): overlaps the barrier wait ----
            #pragma unroll
            for (int it = 8; it < 10; ++it) {
                const int c  = it * 4 + w;
                const int xo = c * 32 - 1024 + kg8;
                f16x8 wf0 = *(const f16x8*)&lds_w[0][c][lane][0];
                f16x8 wf1 = *(const f16x8*)&lds_w[1][c][lane][0];
                #pragma unroll
                for (int bt = 0; bt < 4; ++bt) {
                    f16x8 a = *(const f16x8*)(xt + (size_t)(n + 16 * bt) * (T_DIM * I_DIMM) + xo);
                    acc[0][bt] = __builtin_amdgcn_mfma_f32_16x16x32_f16(a, wf0, acc[0][bt], 0, 0, 0);
                    acc[1][bt] = __builtin_amdgcn_mfma_f32_16x16x32_f16(a, wf1, acc[1][bt], 0, 0, 0);
                }
            }

            // ---- grid barrier wait (flags from end of previous step) ----
            if (tid < NBLK) {
                while (__hip_atomic_load(&flags[tid],
                                         __ATOMIC_RELAXED, __HIP_MEMORY_SCOPE_AGENT) < stepv)
                    __builtin_amdgcn_s_sleep(1);
            }
            __syncthreads();

            // ---- h prefetch: all 32 fragments (64 x 8B sc1) in one burst ----
            u64 hb[64];
            #pragma unroll
            for (int it = 0; it < 8; ++it) {
                const f16* ap = hi + it * 128 + w32 + kg8;
                #pragma unroll
                for (int bt = 0; bt < 4; ++bt) {
                    const u64* p = (const u64*)(ap + (size_t)(n + 16 * bt) * H_DIM);
                    hb[(it * 4 + bt) * 2 + 0] =
                        __hip_atomic_load(p,     __ATOMIC_RELAXED, __HIP_MEMORY_SCOPE_AGENT);
                    hb[(it * 4 + bt) * 2 + 1] =
                        __hip_atomic_load(p + 1, __ATOMIC_RELAXED, __HIP_MEMORY_SCOPE_AGENT);
                }
            }

            // ---- h-part MFMAs ----
            #pragma unroll
            for (int it = 0; it < 8; ++it) {
                const int c = it * 4 + w;
                f16x8 wf0 = *(const f16x8*)&lds_w[0][c][lane][0];
                f16x8 wf1 = *(const f16x8*)&lds_w[1][c][lane][0];
                #pragma unroll
                for (int bt = 0; bt < 4; ++bt) {
                    union { u64 u[2]; f16x8 v; } U;
                    U.u[0] = hb[(it * 4 + bt) * 2 + 0];
                    U.u[1] = hb[(it * 4 + bt) * 2 + 1];
                    acc[0][bt] = __builtin_amdgcn_mfma_f32_16x16x32_f16(U.v, wf0, acc[0][bt], 0, 0, 0);
                    acc[1][bt] = __builtin_amdgcn_mfma_f32_16x16x32_f16(U.v, wf1, acc[1][bt], 0, 0, 0);
                }
            }

            // partials: D row = bt*16 + kg*4 + r, col = ct*16 + n
            #pragma unroll
            for (int ct = 0; ct < 2; ++ct)
                #pragma unroll
                for (int bt = 0; bt < 4; ++bt)
                    #pragma unroll
                    for (int r = 0; r < 4; ++r)
                        gpart[w][bt * 16 + kg * 4 + r][ct * 16 + n] = acc[ct][bt][r];
            __syncthreads();

            // activations + state update for (ab, acol0) and (ab, acol1)
            {
                float p0[4], p1[4];
                #pragma unroll
                for (int g = 0; g < 4; ++g) {
                    p0[g] = gpart[0][ab][g * 8 + jj]     + gpart[1][ab][g * 8 + jj]
                          + gpart[2][ab][g * 8 + jj]     + gpart[3][ab][g * 8 + jj]     + bsum[g][0];
                    p1[g] = gpart[0][ab][g * 8 + jj + 4] + gpart[1][ab][g * 8 + jj + 4]
                          + gpart[2][ab][g * 8 + jj + 4] + gpart[3][ab][g * 8 + jj + 4] + bsum[g][1];
                }
                const float i0 = 1.f / (1.f + expf(-p0[0]));
                const float f0 = 1.f / (1.f + expf(-p0[1]));
                const float g0 = tanhf(p0[2]);
                const float o0 = 1.f / (1.f + expf(-p0[3]));
                c0 = f0 * c0 + i0 * g0;
                h_lds[ab][jj] = (f16)(o0 * tanhf(c0));
                const float i1 = 1.f / (1.f + expf(-p1[0]));
                const float f1 = 1.f / (1.f + expf(-p1[1]));
                const float g1 = tanhf(p1[2]);
                const float o1 = 1.f / (1.f + expf(-p1[3]));
                c1 = f1 * c1 + i1 * g1;
                h_lds[ab][jj + 4] = (f16)(o1 * tanhf(c1));
            }
            __syncthreads();

            // publish this block's 8 h-cols: packed 8B write-through stores
            if (tid < 128) {
                const int b = tid >> 1, half = tid & 1;
                u64 v = *(const u64*)&h_lds[b][half * 4];
                __hip_atomic_store((u64*)(ho + (size_t)b * H_DIM + blk * 8 + half * 4), v,
                                   __ATOMIC_RELAXED, __HIP_MEMORY_SCOPE_AGENT);
            }
            // write-through: vmcnt(0) => globally visible (no wbl2 needed)
            asm volatile("s_waitcnt vmcnt(0)" ::: "memory");
            __syncthreads();

            ++stepv;
            if (tid == 0)
                __hip_atomic_store(&flags[blk], stepv,
                                   __ATOMIC_RELAXED, __HIP_MEMORY_SCOPE_AGENT);
        }
    }
}

// Tail MLP: a = PReLU(additional @ fcc_W^T + fcc_b); out[b] = [dh, a] @ fc_W^T + fc_b
__global__ __launch_bounds__(256) void tail_kernel(
    const f16* __restrict__ dh,        // [64][1024] fp16
    const float* __restrict__ addl,    // [64][128]
    const float* __restrict__ fccW,    // [256][128]
    const float* __restrict__ fccb,    // [256]
    const float* __restrict__ fcW,     // [1][1280]
    const float* __restrict__ fcb,     // [1]
    const float* __restrict__ prelu_a, // [1]
    float* __restrict__ out)           // [64]
{
    __shared__ float a_lds[256];
    __shared__ float red[256];
    const int b = blockIdx.x;
    const int t = threadIdx.x;

    float s = fccb[t];
    const float* wr = fccW + t * 128;
    const float* ar = addl + b * 128;
    #pragma unroll 4
    for (int k = 0; k < 128; ++k) s += ar[k] * wr[k];
    const float pa = *prelu_a;
    a_lds[t] = (s >= 0.f) ? s : pa * s;
    __syncthreads();

    float acc = 0.f;
    for (int k = t; k < 1024; k += 256) acc += (float)dh[b * H_DIM + k] * fcW[k];
    acc += a_lds[t] * fcW[1024 + t];
    red[t] = acc;
    __syncthreads();
    for (int sft = 128; sft > 0; sft >>= 1) {
        if (t < sft) red[t] += red[t + sft];
        __syncthreads();
    }
    if (t == 0) out[b] = red[0] + fcb[0];
}

extern "C" void kernel_launch(void* const* d_in, const int* in_sizes, int n_in,
                              void* d_out, int out_size, void* d_ws, size_t ws_size,
                              hipStream_t stream)
{
    const float* x       = (const float*)d_in[0];
    const float* addl    = (const float*)d_in[1];
    const float* enc_Wih = (const float*)d_in[2];
    const float* enc_Whh = (const float*)d_in[3];
    const float* enc_bih = (const float*)d_in[4];
    const float* enc_bhh = (const float*)d_in[5];
    const float* dec_Wih = (const float*)d_in[6];
    const float* dec_Whh = (const float*)d_in[7];
    const float* dec_bih = (const float*)d_in[8];
    const float* dec_bhh = (const float*)d_in[9];
    const float* fcc_W   = (const float*)d_in[10];
    const float* fcc_b   = (const float*)d_in[11];
    const float* fc_W    = (const float*)d_in[12];
    const float* fc_b    = (const float*)d_in[13];
    const float* prelu_a = (const float*)d_in[14];

    char* wsb = (char*)d_ws;
    const size_t W16_BYTES = (size_t)4 * H_DIM * K_DIM * sizeof(f16);   // 10.5 MB
    const size_t X16_BYTES = (size_t)B_DIM * T_DIM * I_DIMM * sizeof(f16);
    const size_t H16_BYTES = (size_t)B_DIM * H_DIM * sizeof(f16);

    f16* W16e = (f16*)wsb;                      wsb += W16_BYTES;
    f16* W16d = (f16*)wsb;                      wsb += W16_BYTES;
    f16* x16  = (f16*)wsb;                      wsb += X16_BYTES;
    f16* h0   = (f16*)wsb;                      wsb += H16_BYTES;
    f16* h1   = (f16*)wsb;                      wsb += H16_BYTES;
    unsigned* flags = (unsigned*)wsb;

    // One-time (per call) conversions + state init.
    conv_w_kernel<<<4 * H_DIM, 256, 0, stream>>>(enc_Whh, enc_Wih, W16e);
    conv_w_kernel<<<4 * H_DIM, 256, 0, stream>>>(dec_Whh, dec_Wih, W16d);
    conv_x_kernel<<<(B_DIM * T_DIM * I_DIMM / 4 + 255) / 256, 256, 0, stream>>>(
        x, x16, B_DIM * T_DIM * I_DIMM / 4);
    hipMemsetAsync(h0, 0, H16_BYTES, stream);
    hipMemsetAsync(flags, 0, NBLK * sizeof(unsigned), stream);  // epoch 0 each call

    // Persistent cooperative kernel: both LSTMs, 512 steps, one launch.
    {
        void* args[] = { &h0, &h1, &x16, &W16e, &W16d,
                         &enc_bih, &enc_bhh, &dec_bih, &dec_bhh, &flags };
        hipLaunchCooperativeKernel((void*)lstm_persistent, dim3(NBLK), dim3(256),
                                   args, 0, stream);
    }

    // Final dec h is in h0 (256 steps per phase, even count).
    tail_kernel<<<64, 256, 0, stream>>>(h0, addl, fcc_W, fcc_b, fc_W, fc_b,
                                        prelu_a, (float*)d_out);
}

// Round 10
// 5161.863 us; speedup vs baseline: 3.5728x; 1.0584x over previous
//
#include <hip/hip_runtime.h>
#include <cmath>

typedef _Float16 f16;
typedef _Float16 f16x8 __attribute__((ext_vector_type(8)));
typedef _Float16 f16x4 __attribute__((ext_vector_type(4)));
typedef float f32x4 __attribute__((ext_vector_type(4)));
typedef unsigned long long u64;

#define H_DIM 1024
#define I_DIMM 256
#define B_DIM 64
#define T_DIM 256
#define K_DIM 1280
#define NBLK 128   // blocks; each owns 8 h-cols

// Build W16[4096][1280] = fp16([Whh | Wih]) row-major. grid = 4096 blocks.
__global__ __launch_bounds__(256) void conv_w_kernel(const float* __restrict__ Whh,
                                                     const float* __restrict__ Wih,
                                                     f16* __restrict__ W16) {
    const int r = blockIdx.x;
    const int tid = threadIdx.x;
    const float* hh = Whh + (size_t)r * H_DIM;
    const float* ih = Wih + (size_t)r * I_DIMM;
    f16* dst = W16 + (size_t)r * K_DIM;
    for (int k = tid; k < K_DIM; k += 256)
        dst[k] = (f16)(k < H_DIM ? hh[k] : ih[k - H_DIM]);
}

// x fp32 -> fp16, vectorized 4-wide. n4 = total/4.
__global__ __launch_bounds__(256) void conv_x_kernel(const float* __restrict__ x,
                                                     f16* __restrict__ x16, int n4) {
    const int i = blockIdx.x * 256 + threadIdx.x;
    if (i < n4) {
        float4 v = ((const float4*)x)[i];
        f16x4 o;
        o[0] = (f16)v.x; o[1] = (f16)v.y; o[2] = (f16)v.z; o[3] = (f16)v.w;
        ((f16x4*)x16)[i] = o;
    }
}

// sigmoid / tanh via v_exp_f32 + v_rcp_f32 (exact identities):
//   sigmoid(x) = 1/(1+e^-x),  e^-x = 2^(-x*log2 e)
//   tanh(x)    = 1 - 2/(1+e^:2x), e^2x = 2^(x*2*log2 e)
__device__ __forceinline__ float fsig(float x) {
    return __builtin_amdgcn_rcpf(1.f + __builtin_amdgcn_exp2f(-1.442695041f * x));
}
__device__ __forceinline__ float ftanh(float x) {
    return 1.f - 2.f * __builtin_amdgcn_rcpf(1.f + __builtin_amdgcn_exp2f(2.885390082f * x));
}

// Persistent LSTM, both phases, 512 steps, one cooperative launch.
// STRUCTURE IS BYTE-IDENTICAL to the round-7 verified kernel (5.46 ms, passed):
// grid = 128 blocks x 256 threads; block owns h-cols [blk*8,blk*8+8) x 4 gates
// = 32 W rows staged in LDS per phase; K chunk-interleaved across 4 waves;
// x-part at top of iteration (overlaps barrier wait); hb[64] h burst via sc1
// loads; fence-free coherence; flag-array barrier with monotone epochs.
// ONLY two local edits this round:
//   (1) gpart leading stride 33 -> 34 (decl-only; 4-way bank conflict -> free 2-way)
//   (2) OCML expf/tanhf -> fsig/ftanh (v_exp/v_rcp identities)
__global__ __launch_bounds__(256, 1) void lstm_persistent(
    f16* __restrict__ h0,            // [64][1024] ping
    f16* __restrict__ h1,            // [64][1024] pong
    const f16* __restrict__ x16,     // [64][256][256]
    const f16* __restrict__ W16e,    // [4096][1280]
    const f16* __restrict__ W16d,    // [4096][1280]
    const float* __restrict__ enc_bih, const float* __restrict__ enc_bhh,
    const float* __restrict__ dec_bih, const float* __restrict__ dec_bhh,
    unsigned* __restrict__ flags)    // [NBLK], zeroed each call
{
    __shared__ __align__(16) f16 lds_w[2][40][64][8];   // 80 KB  [ct][chunk][lane][8]
    __shared__ float gpart[4][64][34];                  // EDIT(1): stride 34
    __shared__ __align__(16) f16 h_lds[64][8];          // 1 KB

    const int tid  = threadIdx.x;
    const int blk  = blockIdx.x;
    const int w    = tid >> 6;
    const int lane = tid & 63;
    const int n    = lane & 15;
    const int kg   = lane >> 4;
    const int kg8  = kg * 8;
    const int w32  = w * 32;

    // W rows for this lane's two column-tiles (gate-col = ct*16 + n)
    int rW[2];
    #pragma unroll
    for (int ct = 0; ct < 2; ++ct) {
        const int gc = ct * 16 + n;
        rW[ct] = (gc >> 3) * H_DIM + blk * 8 + (gc & 7);
    }

    // activation-thread mapping: thread -> (batch ab, cols jj, jj+4)
    const int ab    = tid >> 2;
    const int jj    = tid & 3;
    const int acol0 = blk * 8 + jj;
    const int acol1 = acol0 + 4;

    float c0 = 0.f, c1 = 0.f;             // cell state, carries enc -> dec
    unsigned stepv = 0;                   // monotone barrier epoch

    #pragma unroll 1
    for (int phase = 0; phase < 2; ++phase) {
        const f16* W  = phase ? W16d : W16e;
        const float* bi = phase ? dec_bih : enc_bih;
        const float* bh = phase ? dec_bhh : enc_bhh;

        float bsum[4][2];
        #pragma unroll
        for (int g = 0; g < 4; ++g) {
            bsum[g][0] = bi[g * H_DIM + acol0] + bh[g * H_DIM + acol0];
            bsum[g][1] = bi[g * H_DIM + acol1] + bh[g * H_DIM + acol1];
        }

        // Stage W chunks (wave-private slots c = it*4+w -> no barrier needed).
        #pragma unroll 1
        for (int it = 0; it < 10; ++it) {
            const int c = it * 4 + w;
            #pragma unroll
            for (int ct = 0; ct < 2; ++ct)
                *(f16x8*)&lds_w[ct][c][lane][0] =
                    *(const f16x8*)(W + (size_t)rW[ct] * K_DIM + c * 32 + kg8);
        }

        #pragma unroll 1
        for (int t = 0; t < T_DIM; ++t) {
            const f16* hi = (t & 1) ? h1 : h0;
            f16*       ho = (t & 1) ? h0 : h1;
            const f16* xt = x16 + (size_t)t * I_DIMM;

            f32x4 acc[2][4];
            #pragma unroll
            for (int ct = 0; ct < 2; ++ct)
                #pragma unroll
                for (int bt = 0; bt < 4; ++bt)
                    acc[ct][bt] = (f32x4){0.f, 0.f, 0.f, 0.f};

            // ---- x-part (h-independent): overlaps the barrier wait ----
            #pragma unroll
            for (int it = 8; it < 10; ++it) {
                const int c  = it * 4 + w;
                const int xo = c * 32 - 1024 + kg8;
                f16x8 wf0 = *(const f16x8*)&lds_w[0][c][lane][0];
                f16x8 wf1 = *(const f16x8*)&lds_w[1][c][lane][0];
                #pragma unroll
                for (int bt = 0; bt < 4; ++bt) {
                    f16x8 a = *(const f16x8*)(xt + (size_t)(n + 16 * bt) * (T_DIM * I_DIMM) + xo);
                    acc[0][bt] = __builtin_amdgcn_mfma_f32_16x16x32_f16(a, wf0, acc[0][bt], 0, 0, 0);
                    acc[1][bt] = __builtin_amdgcn_mfma_f32_16x16x32_f16(a, wf1, acc[1][bt], 0, 0, 0);
                }
            }

            // ---- grid barrier wait (flags from end of previous step) ----
            if (tid < NBLK) {
                while (__hip_atomic_load(&flags[tid],
                                         __ATOMIC_RELAXED, __HIP_MEMORY_SCOPE_AGENT) < stepv)
                    __builtin_amdgcn_s_sleep(1);
            }
            __syncthreads();

            // ---- h prefetch: all 32 fragments (64 x 8B sc1) in one burst ----
            u64 hb[64];
            #pragma unroll
            for (int it = 0; it < 8; ++it) {
                const f16* ap = hi + it * 128 + w32 + kg8;
                #pragma unroll
                for (int bt = 0; bt < 4; ++bt) {
                    const u64* p = (const u64*)(ap + (size_t)(n + 16 * bt) * H_DIM);
                    hb[(it * 4 + bt) * 2 + 0] =
                        __hip_atomic_load(p,     __ATOMIC_RELAXED, __HIP_MEMORY_SCOPE_AGENT);
                    hb[(it * 4 + bt) * 2 + 1] =
                        __hip_atomic_load(p + 1, __ATOMIC_RELAXED, __HIP_MEMORY_SCOPE_AGENT);
                }
            }

            // ---- h-part MFMAs ----
            #pragma unroll
            for (int it = 0; it < 8; ++it) {
                const int c = it * 4 + w;
                f16x8 wf0 = *(const f16x8*)&lds_w[0][c][lane][0];
                f16x8 wf1 = *(const f16x8*)&lds_w[1][c][lane][0];
                #pragma unroll
                for (int bt = 0; bt < 4; ++bt) {
                    union { u64 u[2]; f16x8 v; } U;
                    U.u[0] = hb[(it * 4 + bt) * 2 + 0];
                    U.u[1] = hb[(it * 4 + bt) * 2 + 1];
                    acc[0][bt] = __builtin_amdgcn_mfma_f32_16x16x32_f16(U.v, wf0, acc[0][bt], 0, 0, 0);
                    acc[1][bt] = __builtin_amdgcn_mfma_f32_16x16x32_f16(U.v, wf1, acc[1][bt], 0, 0, 0);
                }
            }

            // partials: D row = bt*16 + kg*4 + r, col = ct*16 + n
            #pragma unroll
            for (int ct = 0; ct < 2; ++ct)
                #pragma unroll
                for (int bt = 0; bt < 4; ++bt)
                    #pragma unroll
                    for (int r = 0; r < 4; ++r)
                        gpart[w][bt * 16 + kg * 4 + r][ct * 16 + n] = acc[ct][bt][r];
            __syncthreads();

            // activations + state update for (ab, acol0) and (ab, acol1)
            {
                float p0[4], p1[4];
                #pragma unroll
                for (int g = 0; g < 4; ++g) {
                    p0[g] = gpart[0][ab][g * 8 + jj]     + gpart[1][ab][g * 8 + jj]
                          + gpart[2][ab][g * 8 + jj]     + gpart[3][ab][g * 8 + jj]     + bsum[g][0];
                    p1[g] = gpart[0][ab][g * 8 + jj + 4] + gpart[1][ab][g * 8 + jj + 4]
                          + gpart[2][ab][g * 8 + jj + 4] + gpart[3][ab][g * 8 + jj + 4] + bsum[g][1];
                }
                // EDIT(2): fast activations, same gate order (i,f,g,o)
                const float i0 = fsig(p0[0]);
                const float f0 = fsig(p0[1]);
                const float g0 = ftanh(p0[2]);
                const float o0 = fsig(p0[3]);
                c0 = f0 * c0 + i0 * g0;
                h_lds[ab][jj] = (f16)(o0 * ftanh(c0));
                const float i1 = fsig(p1[0]);
                const float f1 = fsig(p1[1]);
                const float g1 = ftanh(p1[2]);
                const float o1 = fsig(p1[3]);
                c1 = f1 * c1 + i1 * g1;
                h_lds[ab][jj + 4] = (f16)(o1 * ftanh(c1));
            }
            __syncthreads();

            // publish this block's 8 h-cols: packed 8B write-through stores
            if (tid < 128) {
                const int b = tid >> 1, half = tid & 1;
                u64 v = *(const u64*)&h_lds[b][half * 4];
                __hip_atomic_store((u64*)(ho + (size_t)b * H_DIM + blk * 8 + half * 4), v,
                                   __ATOMIC_RELAXED, __HIP_MEMORY_SCOPE_AGENT);
            }
            // write-through: vmcnt(0) => globally visible (no wbl2 needed)
            asm volatile("s_waitcnt vmcnt(0)" ::: "memory");
            __syncthreads();

            ++stepv;
            if (tid == 0)
                __hip_atomic_store(&flags[blk], stepv,
                                   __ATOMIC_RELAXED, __HIP_MEMORY_SCOPE_AGENT);
        }
    }
}

// Tail MLP: a = PReLU(additional @ fcc_W^T + fcc_b); out[b] = [dh, a] @ fc_W^T + fc_b
__global__ __launch_bounds__(256) void tail_kernel(
    const f16* __restrict__ dh,        // [64][1024] fp16
    const float* __restrict__ addl,    // [64][128]
    const float* __restrict__ fccW,    // [256][128]
    const float* __restrict__ fccb,    // [256]
    const float* __restrict__ fcW,     // [1][1280]
    const float* __restrict__ fcb,     // [1]
    const float* __restrict__ prelu_a, // [1]
    float* __restrict__ out)           // [64]
{
    __shared__ float a_lds[256];
    __shared__ float red[256];
    const int b = blockIdx.x;
    const int t = threadIdx.x;

    float s = fccb[t];
    const float* wr = fccW + t * 128;
    const float* ar = addl + b * 128;
    #pragma unroll 4
    for (int k = 0; k < 128; ++k) s += ar[k] * wr[k];
    const float pa = *prelu_a;
    a_lds[t] = (s >= 0.f) ? s : pa * s;
    __syncthreads();

    float acc = 0.f;
    for (int k = t; k < 1024; k += 256) acc += (float)dh[b * H_DIM + k] * fcW[k];
    acc += a_lds[t] * fcW[1024 + t];
    red[t] = acc;
    __syncthreads();
    for (int sft = 128; sft > 0; sft >>= 1) {
        if (t < sft) red[t] += red[t + sft];
        __syncthreads();
    }
    if (t == 0) out[b] = red[0] + fcb[0];
}

extern "C" void kernel_launch(void* const* d_in, const int* in_sizes, int n_in,
                              void* d_out, int out_size, void* d_ws, size_t ws_size,
                              hipStream_t stream)
{
    const float* x       = (const float*)d_in[0];
    const float* addl    = (const float*)d_in[1];
    const float* enc_Wih = (const float*)d_in[2];
    const float* enc_Whh = (const float*)d_in[3];
    const float* enc_bih = (const float*)d_in[4];
    const float* enc_bhh = (const float*)d_in[5];
    const float* dec_Wih = (const float*)d_in[6];
    const float* dec_Whh = (const float*)d_in[7];
    const float* dec_bih = (const float*)d_in[8];
    const float* dec_bhh = (const float*)d_in[9];
    const float* fcc_W   = (const float*)d_in[10];
    const float* fcc_b   = (const float*)d_in[11];
    const float* fc_W    = (const float*)d_in[12];
    const float* fc_b    = (const float*)d_in[13];
    const float* prelu_a = (const float*)d_in[14];

    char* wsb = (char*)d_ws;
    const size_t W16_BYTES = (size_t)4 * H_DIM * K_DIM * sizeof(f16);   // 10.5 MB
    const size_t X16_BYTES = (size_t)B_DIM * T_DIM * I_DIMM * sizeof(f16);
    const size_t H16_BYTES = (size_t)B_DIM * H_DIM * sizeof(f16);

    f16* W16e = (f16*)wsb;                      wsb += W16_BYTES;
    f16* W16d = (f16*)wsb;                      wsb += W16_BYTES;
    f16* x16  = (f16*)wsb;                      wsb += X16_BYTES;
    f16* h0   = (f16*)wsb;                      wsb += H16_BYTES;
    f16* h1   = (f16*)wsb;                      wsb += H16_BYTES;
    unsigned* flags = (unsigned*)wsb;

    // One-time (per call) conversions + state init.
    conv_w_kernel<<<4 * H_DIM, 256, 0, stream>>>(enc_Whh, enc_Wih, W16e);
    conv_w_kernel<<<4 * H_DIM, 256, 0, stream>>>(dec_Whh, dec_Wih, W16d);
    conv_x_kernel<<<(B_DIM * T_DIM * I_DIMM / 4 + 255) / 256, 256, 0, stream>>>(
        x, x16, B_DIM * T_DIM * I_DIMM / 4);
    hipMemsetAsync(h0, 0, H16_BYTES, stream);
    hipMemsetAsync(flags, 0, NBLK * sizeof(unsigned), stream);  // epoch 0 each call

    // Persistent cooperative kernel: both LSTMs, 512 steps, one launch.
    {
        void* args[] = { &h0, &h1, &x16, &W16e, &W16d,
                         &enc_bih, &enc_bhh, &dec_bih, &dec_bhh, &flags };
        hipLaunchCooperativeKernel((void*)lstm_persistent, dim3(NBLK), dim3(256),
                                   args, 0, stream);
    }

    // Final dec h is in h0 (256 steps per phase, even count).
    tail_kernel<<<64, 256, 0, stream>>>(h0, addl, fcc_W, fcc_b, fc_W, fc_b,
                                        prelu_a, (float*)d_out);
}

// Round 11
// 4983.040 us; speedup vs baseline: 3.7010x; 1.0359x over previous
//
#include <hip/hip_runtime.h>
#include <cmath>

typedef _Float16 f16;
typedef _Float16 f16x8 __attribute__((ext_vector_type(8)));
typedef _Float16 f16x4 __attribute__((ext_vector_type(4)));
typedef float f32x4 __attribute__((ext_vector_type(4)));
typedef unsigned long long u64;

#define H_DIM 1024
#define I_DIMM 256
#define B_DIM 64
#define T_DIM 256
#define K_DIM 1280
#define NBLK 128   // blocks; each owns 8 h-cols

// Build W16[4096][1280] = fp16([Whh | Wih]) row-major. grid = 4096 blocks.
__global__ __launch_bounds__(256) void conv_w_kernel(const float* __restrict__ Whh,
                                                     const float* __restrict__ Wih,
                                                     f16* __restrict__ W16) {
    const int r = blockIdx.x;
    const int tid = threadIdx.x;
    const float* hh = Whh + (size_t)r * H_DIM;
    const float* ih = Wih + (size_t)r * I_DIMM;
    f16* dst = W16 + (size_t)r * K_DIM;
    for (int k = tid; k < K_DIM; k += 256)
        dst[k] = (f16)(k < H_DIM ? hh[k] : ih[k - H_DIM]);
}

// x fp32 -> fp16, vectorized 4-wide. n4 = total/4.
__global__ __launch_bounds__(256) void conv_x_kernel(const float* __restrict__ x,
                                                     f16* __restrict__ x16, int n4) {
    const int i = blockIdx.x * 256 + threadIdx.x;
    if (i < n4) {
        float4 v = ((const float4*)x)[i];
        f16x4 o;
        o[0] = (f16)v.x; o[1] = (f16)v.y; o[2] = (f16)v.z; o[3] = (f16)v.w;
        ((f16x4*)x16)[i] = o;
    }
}

// sigmoid / tanh via v_exp_f32 + v_rcp_f32 (exact identities)
__device__ __forceinline__ float fsig(float x) {
    return __builtin_amdgcn_rcpf(1.f + __builtin_amdgcn_exp2f(-1.442695041f * x));
}
__device__ __forceinline__ float ftanh(float x) {
    return 1.f - 2.f * __builtin_amdgcn_rcpf(1.f + __builtin_amdgcn_exp2f(2.885390082f * x));
}

// Persistent LSTM, both phases, 512 steps, one cooperative launch.
// ROUND-11 CHANGE (single axis vs the round-10 verified kernel): 512 threads
// = 8 waves; wave = (bh = w>>2 batch-half, kq = w&3 K-quarter).
//   - per-wave h burst: 32 u64 (was 64) -> real load window, 2x outstanding/CU
//   - activations: 512 threads, one gate-column each (was 2 per thread)
//   - W staging split: bh=0 stages chunk-iters 0..4, bh=1 stages 5..9, then
//     ONE __syncthreads (slots are no longer wave-private to the reader).
// Exchange machinery (h ping/pong, sc1 write-through publish + sc1 bypass
// loads, vmcnt(0) drain, flag-array barrier with monotone epochs) is
// byte-identical to round 10.
__global__ __launch_bounds__(512, 1) void lstm_persistent(
    f16* __restrict__ h0,            // [64][1024] ping
    f16* __restrict__ h1,            // [64][1024] pong
    const f16* __restrict__ x16,     // [64][256][256]
    const f16* __restrict__ W16e,    // [4096][1280]
    const f16* __restrict__ W16d,    // [4096][1280]
    const float* __restrict__ enc_bih, const float* __restrict__ enc_bhh,
    const float* __restrict__ dec_bih, const float* __restrict__ dec_bhh,
    unsigned* __restrict__ flags)    // [NBLK], zeroed each call
{
    __shared__ __align__(16) f16 lds_w[2][40][64][8];   // 80 KB  [ct][chunk][lane][8]
    __shared__ float gpart[4][64][34];                  // 34.8 KB [kq][batch][gatecol]
    __shared__ __align__(16) f16 h_lds[64][8];          // 1 KB

    const int tid  = threadIdx.x;
    const int blk  = blockIdx.x;
    const int w    = tid >> 6;
    const int bh   = w >> 2;              // batch half (0: rows 0-31, 1: 32-63)
    const int kq   = w & 3;               // K quarter
    const int lane = tid & 63;
    const int n    = lane & 15;
    const int kg   = lane >> 4;
    const int kg8  = kg * 8;
    const int kq32 = kq * 32;

    // W rows for this lane's two column-tiles (gate-col = ct*16 + n)
    int rW[2];
    #pragma unroll
    for (int ct = 0; ct < 2; ++ct) {
        const int gc = ct * 16 + n;
        rW[ct] = (gc >> 3) * H_DIM + blk * 8 + (gc & 7);
    }

    // activation-thread mapping: one (batch, col) per thread
    const int ab   = tid >> 3;
    const int aj   = tid & 7;
    const int acol = blk * 8 + aj;

    float c_reg = 0.f;                    // cell state, carries enc -> dec
    unsigned stepv = 0;                   // monotone barrier epoch

    #pragma unroll 1
    for (int phase = 0; phase < 2; ++phase) {
        const f16* W  = phase ? W16d : W16e;
        const float* bi = phase ? dec_bih : enc_bih;
        const float* bhp = phase ? dec_bhh : enc_bhh;

        float bsum[4];
        #pragma unroll
        for (int g = 0; g < 4; ++g)
            bsum[g] = bi[g * H_DIM + acol] + bhp[g * H_DIM + acol];

        // Stage W chunks: bh=0 waves stage iters 0..4, bh=1 waves iters 5..9.
        // Readers cross bh -> one block barrier after staging.
        {
            const int it0 = bh * 5;
            #pragma unroll 1
            for (int i = 0; i < 5; ++i) {
                const int c = (it0 + i) * 4 + kq;
                #pragma unroll
                for (int ct = 0; ct < 2; ++ct)
                    *(f16x8*)&lds_w[ct][c][lane][0] =
                        *(const f16x8*)(W + (size_t)rW[ct] * K_DIM + c * 32 + kg8);
            }
        }
        __syncthreads();

        #pragma unroll 1
        for (int t = 0; t < T_DIM; ++t) {
            const f16* hi = (t & 1) ? h1 : h0;
            f16*       ho = (t & 1) ? h0 : h1;
            const f16* xt = x16 + (size_t)t * I_DIMM;

            f32x4 acc[2][2];   // [ct][btl]
            #pragma unroll
            for (int ct = 0; ct < 2; ++ct)
                #pragma unroll
                for (int btl = 0; btl < 2; ++btl)
                    acc[ct][btl] = (f32x4){0.f, 0.f, 0.f, 0.f};

            // ---- x-part (h-independent): overlaps the barrier wait ----
            #pragma unroll
            for (int it = 8; it < 10; ++it) {
                const int c  = it * 4 + kq;
                const int xo = c * 32 - 1024 + kg8;
                f16x8 wf0 = *(const f16x8*)&lds_w[0][c][lane][0];
                f16x8 wf1 = *(const f16x8*)&lds_w[1][c][lane][0];
                #pragma unroll
                for (int btl = 0; btl < 2; ++btl) {
                    const int btg = bh * 2 + btl;
                    f16x8 a = *(const f16x8*)(xt + (size_t)(n + 16 * btg) * (T_DIM * I_DIMM) + xo);
                    acc[0][btl] = __builtin_amdgcn_mfma_f32_16x16x32_f16(a, wf0, acc[0][btl], 0, 0, 0);
                    acc[1][btl] = __builtin_amdgcn_mfma_f32_16x16x32_f16(a, wf1, acc[1][btl], 0, 0, 0);
                }
            }

            // ---- grid barrier wait (flags from end of previous step) ----
            if (tid < NBLK) {
                while (__hip_atomic_load(&flags[tid],
                                         __ATOMIC_RELAXED, __HIP_MEMORY_SCOPE_AGENT) < stepv)
                    __builtin_amdgcn_s_sleep(1);
            }
            __syncthreads();

            // ---- h burst: 16 fragments (32 x 8B sc1) per lane ----
            u64 hb[32];
            #pragma unroll
            for (int it = 0; it < 8; ++it) {
                const f16* ap = hi + it * 128 + kq32 + kg8;
                #pragma unroll
                for (int btl = 0; btl < 2; ++btl) {
                    const int btg = bh * 2 + btl;
                    const u64* p = (const u64*)(ap + (size_t)(n + 16 * btg) * H_DIM);
                    hb[(it * 2 + btl) * 2 + 0] =
                        __hip_atomic_load(p,     __ATOMIC_RELAXED, __HIP_MEMORY_SCOPE_AGENT);
                    hb[(it * 2 + btl) * 2 + 1] =
                        __hip_atomic_load(p + 1, __ATOMIC_RELAXED, __HIP_MEMORY_SCOPE_AGENT);
                }
            }

            // ---- h-part MFMAs ----
            #pragma unroll
            for (int it = 0; it < 8; ++it) {
                const int c = it * 4 + kq;
                f16x8 wf0 = *(const f16x8*)&lds_w[0][c][lane][0];
                f16x8 wf1 = *(const f16x8*)&lds_w[1][c][lane][0];
                #pragma unroll
                for (int btl = 0; btl < 2; ++btl) {
                    union { u64 u[2]; f16x8 v; } U;
                    U.u[0] = hb[(it * 2 + btl) * 2 + 0];
                    U.u[1] = hb[(it * 2 + btl) * 2 + 1];
                    acc[0][btl] = __builtin_amdgcn_mfma_f32_16x16x32_f16(U.v, wf0, acc[0][btl], 0, 0, 0);
                    acc[1][btl] = __builtin_amdgcn_mfma_f32_16x16x32_f16(U.v, wf1, acc[1][btl], 0, 0, 0);
                }
            }

            // partials: D row = (bh*2+btl)*16 + kg*4 + r, col = ct*16 + n
            // (each gpart[kq] row range [32bh,32bh+32) written by exactly one wave)
            #pragma unroll
            for (int ct = 0; ct < 2; ++ct)
                #pragma unroll
                for (int btl = 0; btl < 2; ++btl)
                    #pragma unroll
                    for (int r = 0; r < 4; ++r)
                        gpart[kq][(bh * 2 + btl) * 16 + kg * 4 + r][ct * 16 + n] = acc[ct][btl][r];
            __syncthreads();

            // ---- activations + state update: one (batch, col) per thread ----
            {
                float pre[4];
                #pragma unroll
                for (int g = 0; g < 4; ++g)
                    pre[g] = gpart[0][ab][g * 8 + aj] + gpart[1][ab][g * 8 + aj]
                           + gpart[2][ab][g * 8 + aj] + gpart[3][ab][g * 8 + aj] + bsum[g];
                const float i_ = fsig(pre[0]);
                const float f_ = fsig(pre[1]);
                const float g_ = ftanh(pre[2]);
                const float o_ = fsig(pre[3]);
                c_reg = f_ * c_reg + i_ * g_;
                h_lds[ab][aj] = (f16)(o_ * ftanh(c_reg));
            }
            __syncthreads();

            // publish this block's 8 h-cols: packed 8B write-through stores
            if (tid < 128) {
                const int b = tid >> 1, half = tid & 1;
                u64 v = *(const u64*)&h_lds[b][half * 4];
                __hip_atomic_store((u64*)(ho + (size_t)b * H_DIM + blk * 8 + half * 4), v,
                                   __ATOMIC_RELAXED, __HIP_MEMORY_SCOPE_AGENT);
            }
            // write-through: vmcnt(0) => globally visible (no wbl2 needed)
            asm volatile("s_waitcnt vmcnt(0)" ::: "memory");
            __syncthreads();

            ++stepv;
            if (tid == 0)
                __hip_atomic_store(&flags[blk], stepv,
                                   __ATOMIC_RELAXED, __HIP_MEMORY_SCOPE_AGENT);
        }
    }
}

// Tail MLP: a = PReLU(additional @ fcc_W^T + fcc_b); out[b] = [dh, a] @ fc_W^T + fc_b
__global__ __launch_bounds__(256) void tail_kernel(
    const f16* __restrict__ dh,        // [64][1024] fp16
    const float* __restrict__ addl,    // [64][128]
    const float* __restrict__ fccW,    // [256][128]
    const float* __restrict__ fccb,    // [256]
    const float* __restrict__ fcW,     // [1][1280]
    const float* __restrict__ fcb,     // [1]
    const float* __restrict__ prelu_a, // [1]
    float* __restrict__ out)           // [64]
{
    __shared__ float a_lds[256];
    __shared__ float red[256];
    const int b = blockIdx.x;
    const int t = threadIdx.x;

    float s = fccb[t];
    const float* wr = fccW + t * 128;
    const float* ar = addl + b * 128;
    #pragma unroll 4
    for (int k = 0; k < 128; ++k) s += ar[k] * wr[k];
    const float pa = *prelu_a;
    a_lds[t] = (s >= 0.f) ? s : pa * s;
    __syncthreads();

    float acc = 0.f;
    for (int k = t; k < 1024; k += 256) acc += (float)dh[b * H_DIM + k] * fcW[k];
    acc += a_lds[t] * fcW[1024 + t];
    red[t] = acc;
    __syncthreads();
    for (int sft = 128; sft > 0; sft >>= 1) {
        if (t < sft) red[t] += red[t + sft];
        __syncthreads();
    }
    if (t == 0) out[b] = red[0] + fcb[0];
}

extern "C" void kernel_launch(void* const* d_in, const int* in_sizes, int n_in,
                              void* d_out, int out_size, void* d_ws, size_t ws_size,
                              hipStream_t stream)
{
    const float* x       = (const float*)d_in[0];
    const float* addl    = (const float*)d_in[1];
    const float* enc_Wih = (const float*)d_in[2];
    const float* enc_Whh = (const float*)d_in[3];
    const float* enc_bih = (const float*)d_in[4];
    const float* enc_bhh = (const float*)d_in[5];
    const float* dec_Wih = (const float*)d_in[6];
    const float* dec_Whh = (const float*)d_in[7];
    const float* dec_bih = (const float*)d_in[8];
    const float* dec_bhh = (const float*)d_in[9];
    const float* fcc_W   = (const float*)d_in[10];
    const float* fcc_b   = (const float*)d_in[11];
    const float* fc_W    = (const float*)d_in[12];
    const float* fc_b    = (const float*)d_in[13];
    const float* prelu_a = (const float*)d_in[14];

    char* wsb = (char*)d_ws;
    const size_t W16_BYTES = (size_t)4 * H_DIM * K_DIM * sizeof(f16);   // 10.5 MB
    const size_t X16_BYTES = (size_t)B_DIM * T_DIM * I_DIMM * sizeof(f16);
    const size_t H16_BYTES = (size_t)B_DIM * H_DIM * sizeof(f16);

    f16* W16e = (f16*)wsb;                      wsb += W16_BYTES;
    f16* W16d = (f16*)wsb;                      wsb += W16_BYTES;
    f16* x16  = (f16*)wsb;                      wsb += X16_BYTES;
    f16* h0   = (f16*)wsb;                      wsb += H16_BYTES;
    f16* h1   = (f16*)wsb;                      wsb += H16_BYTES;
    unsigned* flags = (unsigned*)wsb;

    // One-time (per call) conversions + state init.
    conv_w_kernel<<<4 * H_DIM, 256, 0, stream>>>(enc_Whh, enc_Wih, W16e);
    conv_w_kernel<<<4 * H_DIM, 256, 0, stream>>>(dec_Whh, dec_Wih, W16d);
    conv_x_kernel<<<(B_DIM * T_DIM * I_DIMM / 4 + 255) / 256, 256, 0, stream>>>(
        x, x16, B_DIM * T_DIM * I_DIMM / 4);
    hipMemsetAsync(h0, 0, H16_BYTES, stream);
    hipMemsetAsync(flags, 0, NBLK * sizeof(unsigned), stream);  // epoch 0 each call

    // Persistent cooperative kernel: both LSTMs, 512 steps, one launch.
    {
        void* args[] = { &h0, &h1, &x16, &W16e, &W16d,
                         &enc_bih, &enc_bhh, &dec_bih, &dec_bhh, &flags };
        hipLaunchCooperativeKernel((void*)lstm_persistent, dim3(NBLK), dim3(512),
                                   args, 0, stream);
    }

    // Final dec h is in h0 (256 steps per phase, even count).
    tail_kernel<<<64, 256, 0, stream>>>(h0, addl, fcc_W, fcc_b, fc_W, fc_b,
                                        prelu_a, (float*)d_out);
}